// Round 5
// baseline (386.586 us; speedup 1.0000x reference)
//
#include <hip/hip_runtime.h>
#include <hip/hip_bf16.h>
#include <hip/hip_cooperative_groups.h>

namespace cg = cooperative_groups;

typedef __hip_bfloat16 bf16;
typedef unsigned short u16;
typedef __attribute__((ext_vector_type(8))) short bf16x8;     // MFMA A/B frag: 8 bf16 = 4 VGPRs
typedef __attribute__((ext_vector_type(4))) float f32x4;      // MFMA C/D frag
typedef __attribute__((ext_vector_type(8))) unsigned short u16x8;

#define KD 1024
#define HD 1024
#define BSZ 8192
#define BM 128
#define BN 64
#define BK 32

// ws layout (bytes): wt [0, 12582912) | xb [12582912, +16777216) | hb [29360128, +16777216)
#define WS_XB 12582912
#define WS_HB 29360128
#define WS_NEED 46137344ULL

#define NTRB 1536          // transpose job count (6 gates x 256 tiles)
#define COOP_GRID 512      // 2 blocks/CU x 256 CU -> all co-resident

__device__ __forceinline__ u16 f2b(float f) {
    return __builtin_bit_cast(u16, __float2bfloat16(f));
}

// ---- async global->LDS, 16B per lane, wave-uniform LDS base + lane*16 ----
__device__ __forceinline__ void gload16(const void* g, u16* smem, int lds_byte_off) {
    __builtin_amdgcn_global_load_lds(
        (const __attribute__((address_space(1))) void*)g,
        (__attribute__((address_space(3))) void*)((char*)smem + lds_byte_off),
        16, 0, 0);
}

// ---------------------------------------------------------------------------
// Prep jobs (device functions shared by coop kernel and fallback prep kernel)
// ---------------------------------------------------------------------------
// transpose job jj in [0,1536): one 64x64 tile of w [g][k][n] f32 -> wt[g][n][k]
// bf16. f32 LDS tile [64][69]: 69 mod 32 = 5 makes both sides conflict-free.
__device__ __forceinline__ void transpose_job(
    int jj, const float* wx, const float* wh, u16* wt, float* tile, int t)
{
    const int g  = jj >> 8;
    const int rm = jj & 255;
    const int r0 = (rm >> 4) * 64;   // k origin in src
    const int c0 = (rm & 15) * 64;   // n origin in src
    const float* src = (g < 3) ? (wx + (size_t)g * KD * HD)
                               : (wh + (size_t)(g - 3) * KD * HD);
    u16* dst = wt + (size_t)g * KD * HD;

    #pragma unroll
    for (int ps = 0; ps < 4; ps++) {
        int idx = ps * 256 + t;
        int row = idx >> 4;              // k row 0..63
        int c4  = (idx & 15) * 4;        // 4 n per thread
        float4 v = *(const float4*)(src + (size_t)(r0 + row) * HD + c0 + c4);
        *(float4*)&tile[row * 69 + c4] = v;
    }
    __syncthreads();
    const int n = t >> 2;                // output n-row 0..63
    #pragma unroll
    for (int p = 0; p < 2; p++) {
        int k0 = (t & 3) * 8 + p * 32;   // 8 k per store
        u16x8 v;
        #pragma unroll
        for (int e = 0; e < 8; e++)
            v[e] = f2b(tile[(k0 + e) * 69 + n]);
        *(u16x8*)(dst + (size_t)(c0 + n) * KD + r0 + k0) = v;
    }
}

// convert job cidx in [0,4096): 2048-float chunk of x and hid f32 -> bf16.
__device__ __forceinline__ void convert_job(
    int cidx, const float* x, const float* h, u16* xb, u16* hb, int t)
{
    size_t off = ((size_t)cidx * 256 + t) * 8;
    float4 a0 = *(const float4*)(x + off);
    float4 a1 = *(const float4*)(x + off + 4);
    float4 b0 = *(const float4*)(h + off);
    float4 b1 = *(const float4*)(h + off + 4);
    u16x8 vx, vh;
    vx[0]=f2b(a0.x); vx[1]=f2b(a0.y); vx[2]=f2b(a0.z); vx[3]=f2b(a0.w);
    vx[4]=f2b(a1.x); vx[5]=f2b(a1.y); vx[6]=f2b(a1.z); vx[7]=f2b(a1.w);
    vh[0]=f2b(b0.x); vh[1]=f2b(b0.y); vh[2]=f2b(b0.z); vh[3]=f2b(b0.w);
    vh[4]=f2b(b1.x); vh[5]=f2b(b1.y); vh[6]=f2b(b1.z); vh[7]=f2b(b1.w);
    *(u16x8*)(xb + off) = vx;
    *(u16x8*)(hb + off) = vh;
}

// ---------------------------------------------------------------------------
// Epilogue. C/D layout: col=lane&15, row=quad*4+r.
// ---------------------------------------------------------------------------
__device__ __forceinline__ void gru_epilogue(
    f32x4 (&acc)[4][4][2], const float* __restrict__ bxf, const float* __restrict__ bhf,
    const float* __restrict__ hidf, float* __restrict__ outf,
    int m0, int n0, int wm, int wn, int quad, int c16)
{
    float bR[2], bZ[2], bXN[2], bHN[2];
    #pragma unroll
    for (int j = 0; j < 2; j++) {
        int col = n0 + wn * 32 + j * 16 + c16;
        bR[j]  = bxf[col]          + bhf[col];
        bZ[j]  = bxf[HD + col]     + bhf[HD + col];
        bXN[j] = bxf[2 * HD + col];
        bHN[j] = bhf[2 * HD + col];
    }
    #pragma unroll
    for (int i = 0; i < 4; i++)
        #pragma unroll
        for (int j = 0; j < 2; j++) {
            int col = n0 + wn * 32 + j * 16 + c16;
            #pragma unroll
            for (int r = 0; r < 4; r++) {
                int row = m0 + wm * 64 + i * 16 + quad * 4 + r;
                size_t idx = (size_t)row * HD + col;
                float vr = acc[0][i][j][r] + bR[j];
                vr = 1.f / (1.f + __expf(-vr));
                float vz = acc[1][i][j][r] + bZ[j];
                vz = 1.f / (1.f + __expf(-vz));
                float vn = (acc[2][i][j][r] + bXN[j]) + vr * (acc[3][i][j][r] + bHN[j]);
                float e2 = __expf(2.f * vn);
                vn = 1.f - 2.f / (e2 + 1.f);
                float o = (1.f - vz) * vn + vz * hidf[idx];
                outf[idx] = o;
            }
        }
}

// ---------------------------------------------------------------------------
// Stage one K-step (BK=32) tile set into LDS buffer at byte base `bufb`.
// x0 [0,4K) x1 [4K,8K) h0 [8K,12K) h1 [12K,16K) w[g] at 16K+g*4K = 40960 B.
// Global sources are PRE-SWIZZLED (16B k-slot XOR'd with row bits) so the
// linear global_load_lds write produces the swizzled layout.
// ---------------------------------------------------------------------------
__device__ __forceinline__ void kstep_stage(
    const u16* gx0, const u16* gx1, const u16* gh0, const u16* gh1,
    const u16* gw0, u16* smem, int bufb, int ldsl)
{
    gload16(gx0, smem, bufb + ldsl);
    gload16(gx1, smem, bufb + 4096 + ldsl);
    gload16(gh0, smem, bufb + 8192 + ldsl);
    gload16(gh1, smem, bufb + 12288 + ldsl);
    #pragma unroll
    for (int g = 0; g < 6; g++)
        gload16(gw0 + (size_t)g * KD * HD, smem, bufb + 16384 + g * 4096 + ldsl);
}

// ---------------------------------------------------------------------------
// Compute one K-step. Reads use phys_slot = quad ^ ((row>>1)&3): conflicts
// verified 0 on HW (R2/R3).
// ---------------------------------------------------------------------------
__device__ __forceinline__ void kstep_compute(
    const u16* sm, f32x4 (&acc)[4][4][2], int wm, int wn, int quad, int c16)
{
    bf16x8 ax[4], ah[4];
    #pragma unroll
    for (int i = 0; i < 4; i++) {
        int ml = wm * 64 + i * 16 + c16;
        int sl = (quad ^ ((ml >> 1) & 3)) * 8;
        ax[i] = *(const bf16x8*)&sm[ml * BK + sl];
        ah[i] = *(const bf16x8*)&sm[4096 + ml * BK + sl];
    }
    #pragma unroll
    for (int p = 0; p < 3; p++) {
        bf16x8 bwx[2], bwh[2];
        #pragma unroll
        for (int j = 0; j < 2; j++) {
            int nl = wn * 32 + j * 16 + c16;
            int sl = (quad ^ ((nl >> 1) & 3)) * 8;
            bwx[j] = *(const bf16x8*)&sm[8192 + p * 2048       + nl * BK + sl];
            bwh[j] = *(const bf16x8*)&sm[8192 + (p + 3) * 2048 + nl * BK + sl];
        }
        #pragma unroll
        for (int i = 0; i < 4; i++)
            #pragma unroll
            for (int j = 0; j < 2; j++) {
                if (p < 2) {
                    acc[p][i][j] = __builtin_amdgcn_mfma_f32_16x16x32_bf16(ax[i], bwx[j], acc[p][i][j], 0, 0, 0);
                    acc[p][i][j] = __builtin_amdgcn_mfma_f32_16x16x32_bf16(ah[i], bwh[j], acc[p][i][j], 0, 0, 0);
                } else {
                    acc[2][i][j] = __builtin_amdgcn_mfma_f32_16x16x32_bf16(ax[i], bwx[j], acc[2][i][j], 0, 0, 0);
                    acc[3][i][j] = __builtin_amdgcn_mfma_f32_16x16x32_bf16(ah[i], bwh[j], acc[3][i][j], 0, 0, 0);
                }
            }
    }
}

// ---------------------------------------------------------------------------
// One full GEMM output tile (the proven R3 structure: double-buffered 2-phase,
// fully swizzled, one barrier per K-step). 122.9 us / MfmaUtil 37% / 0 confl.
// ---------------------------------------------------------------------------
__device__ __forceinline__ void gemm_tile(
    int lin, u16* smem,
    const u16* xb, const u16* hb, const u16* wt,
    const float* bxf, const float* bhf, const float* hidf, float* outf, int t)
{
    const int lane = t & 63;
    const int w    = t >> 6;
    const int wm   = w >> 1, wn = w & 1;
    const int quad = lane >> 4;
    const int c16  = lane & 15;
    // XCD swizzle: linear % 8 presumed XCD; each XCD owns 2 n-blocks so its
    // 1.57 MB weight slice stays L2-resident.
    const int nblk = (lin & 7) * 2 + ((lin >> 3) & 1);
    const int mblk = lin >> 4;
    const int m0   = mblk * BM;
    const int n0   = nblk * BN;

    const int row4 = t >> 2;
    const int e8s  = ((t & 3) ^ ((t >> 3) & 3)) * 8;
    const u16* gx0 = xb + (size_t)(m0 + row4) * KD + e8s;
    const u16* gx1 = gx0 + (size_t)64 * KD;
    const u16* gh0 = hb + (size_t)(m0 + row4) * KD + e8s;
    const u16* gh1 = gh0 + (size_t)64 * KD;
    const u16* gw0 = wt + (size_t)(n0 + row4) * KD + e8s;
    const int ldsl = w * 1024;   // wave-uniform LDS byte base (lane adds *16)

    f32x4 acc[4][4][2];
    #pragma unroll
    for (int a = 0; a < 4; a++)
        #pragma unroll
        for (int i = 0; i < 4; i++)
            #pragma unroll
            for (int j = 0; j < 2; j++)
                acc[a][i][j] = (f32x4){0.f, 0.f, 0.f, 0.f};

    const int NT = KD / BK;   // 32

    kstep_stage(gx0, gx1, gh0, gh1, gw0, smem, 0, ldsl);
    gx0 += BK; gx1 += BK; gh0 += BK; gh1 += BK; gw0 += BK;
    __syncthreads();

    for (int tt = 0; tt < NT - 1; ++tt) {
        kstep_stage(gx0, gx1, gh0, gh1, gw0, smem, ((tt + 1) & 1) * 40960, ldsl);
        gx0 += BK; gx1 += BK; gh0 += BK; gh1 += BK; gw0 += BK;
        kstep_compute(smem + (tt & 1) * 20480, acc, wm, wn, quad, c16);
        __syncthreads();
    }
    kstep_compute(smem + 20480, acc, wm, wn, quad, c16);

    gru_epilogue(acc, bxf, bhf, hidf, outf, m0, n0, wm, wn, quad, c16);
}

// ---------------------------------------------------------------------------
// Cooperative single-launch kernel: phase 1 = prep (3 transpose + 8 convert
// jobs per block), grid-wide sync, phase 2 = 2 GEMM tiles per block.
// half=0/1 give the same nblk (512 % 16 == 0 in the swizzle) -> each block's
// weight slice is fetched once and reused for both tiles.
// Safety at the half boundary: half-0's last compute reads buf1; half-1's
// prologue stages buf0 (last read before the loop's final barrier) and its
// prologue __syncthreads orders everything before buf1 is restaged.
// ---------------------------------------------------------------------------
__global__ __launch_bounds__(256, 2) void gru_coop(
    const float* __restrict__ wx, const float* __restrict__ wh, u16* __restrict__ wt,
    const float* __restrict__ x, const float* __restrict__ hidf,
    u16* __restrict__ xb, u16* __restrict__ hb,
    const float* __restrict__ bxf, const float* __restrict__ bhf,
    float* __restrict__ outf)
{
    __shared__ u16 smem[40960];   // 80 KiB: GEMM double buffer; aliased by prep tile
    const int t = threadIdx.x;
    const int b = blockIdx.x;

    // ---- phase 1: prep ----
    {
        float* tile = (float*)smem;   // 64*69*4 = 17664 B < 80 KiB
        #pragma unroll
        for (int i = 0; i < 3; i++) {
            if (i) __syncthreads();   // WAR on tile reuse
            transpose_job(b + COOP_GRID * i, wx, wh, wt, tile, t);
        }
        #pragma unroll
        for (int i = 0; i < 8; i++)
            convert_job(b + COOP_GRID * i, x, hidf, xb, hb, t);
    }
    __threadfence();                  // make wt/xb/hb visible device-wide
    cg::this_grid().sync();

    // ---- phase 2: GEMM, 2 tiles per block ----
    gemm_tile(b,             smem, xb, hb, wt, bxf, bhf, hidf, outf, t);
    gemm_tile(b + COOP_GRID, smem, xb, hb, wt, bxf, bhf, hidf, outf, t);
}

// ---------------------------------------------------------------------------
// Fallback kernels (used if cooperative launch is unavailable, or ws small).
// ---------------------------------------------------------------------------
__global__ __launch_bounds__(256) void prep(
    const float* __restrict__ wx, const float* __restrict__ wh, u16* __restrict__ wt,
    const float* __restrict__ x, const float* __restrict__ h,
    u16* __restrict__ xb, u16* __restrict__ hb)
{
    __shared__ float tile[64 * 69];
    const int b = blockIdx.x;
    const int t = threadIdx.x;
    if (b < NTRB) transpose_job(b, wx, wh, wt, tile, t);
    else          convert_job(b - NTRB, x, h, xb, hb, t);
}

__global__ __launch_bounds__(256, 2) void gru_fused_fast(
    const u16* __restrict__ xb, const u16* __restrict__ hb,
    const u16* __restrict__ wt,
    const float* __restrict__ bxf, const float* __restrict__ bhf,
    const float* __restrict__ hidf, float* __restrict__ outf)
{
    __shared__ u16 smem[40960];
    gemm_tile(blockIdx.x, smem, xb, hb, wt, bxf, bhf, hidf, outf, threadIdx.x);
}

// ws-too-small path: in-loop f32->bf16 convert for x/h (swizzled ds_write);
// weights via pre-swizzled global_load_lds. Single-buffer.
__global__ __launch_bounds__(256, 2) void gru_fused_slow(
    const float* __restrict__ xf, const float* __restrict__ hf,
    const u16* __restrict__ wt,
    const float* __restrict__ bxf, const float* __restrict__ bhf,
    float* __restrict__ outf)
{
    __shared__ u16 smem[20480];
    const int t    = threadIdx.x;
    const int lane = t & 63;
    const int w    = t >> 6;
    const int wm   = w >> 1, wn = w & 1;
    const int quad = lane >> 4;
    const int c16  = lane & 15;
    const int lin  = blockIdx.x;
    const int nblk = (lin & 7) * 2 + ((lin >> 3) & 1);
    const int mblk = lin >> 4;
    const int m0   = mblk * BM;
    const int n0   = nblk * BN;
    const int row4 = t >> 2;
    const int e8s  = ((t & 3) ^ ((t >> 3) & 3)) * 8;
    const u16* gw0 = wt + (size_t)(n0 + row4) * KD + e8s;
    const int ldsl = w * 1024;

    f32x4 acc[4][4][2];
    #pragma unroll
    for (int a = 0; a < 4; a++)
        #pragma unroll
        for (int i = 0; i < 4; i++)
            #pragma unroll
            for (int j = 0; j < 2; j++)
                acc[a][i][j] = (f32x4){0.f, 0.f, 0.f, 0.f};

    for (int k0 = 0; k0 < KD; k0 += BK) {
        #pragma unroll
        for (int g = 0; g < 6; g++)
            gload16(gw0 + (size_t)g * KD * HD, smem, 16384 + g * 4096 + ldsl);
        gw0 += BK;
        #pragma unroll
        for (int s = 0; s < 2; s++) {
            size_t gidx = (size_t)(m0 + s * 64 + row4) * KD + k0 + (t & 3) * 8;
            const float* px = xf + gidx;
            const float* ph = hf + gidx;
            u16x8 vx, vh;
            #pragma unroll
            for (int e = 0; e < 8; e++) { vx[e] = f2b(px[e]); vh[e] = f2b(ph[e]); }
            *(u16x8*)&smem[s * 2048 + row4 * 32 + e8s] = vx;
            *(u16x8*)&smem[4096 + s * 2048 + row4 * 32 + e8s] = vh;
        }
        __syncthreads();
        kstep_compute(smem, acc, wm, wn, quad, c16);
        __syncthreads();
    }

    gru_epilogue(acc, bxf, bhf, hf, outf, m0, n0, wm, wn, quad, c16);
}

extern "C" void kernel_launch(void* const* d_in, const int* in_sizes, int n_in,
                              void* d_out, int out_size, void* d_ws, size_t ws_size,
                              hipStream_t stream) {
    const float* x   = (const float*)d_in[0];
    const float* hid = (const float*)d_in[1];
    const float* wx  = (const float*)d_in[2];
    const float* wh  = (const float*)d_in[3];
    const float* bx  = (const float*)d_in[4];
    const float* bh  = (const float*)d_in[5];
    float* out = (float*)d_out;

    char* ws = (char*)d_ws;
    u16* wt = (u16*)ws;
    u16* xb = (u16*)(ws + WS_XB);
    u16* hb = (u16*)(ws + WS_HB);

    if (ws_size >= WS_NEED) {
        void* args[] = {
            (void*)&wx, (void*)&wh, (void*)&wt, (void*)&x, (void*)&hid,
            (void*)&xb, (void*)&hb, (void*)&bx, (void*)&bh, (void*)&out
        };
        hipError_t err = hipLaunchCooperativeKernel(
            (const void*)gru_coop, dim3(COOP_GRID), dim3(256), args, 0, stream);
        if (err != hipSuccess) {
            (void)hipGetLastError();   // clear; fall back to 2-launch path
            prep<<<NTRB + 4096, 256, 0, stream>>>(wx, wh, wt, x, hid, xb, hb);
            gru_fused_fast<<<1024, 256, 0, stream>>>(xb, hb, wt, bx, bh, hid, out);
        }
    } else {
        prep<<<NTRB, 256, 0, stream>>>(wx, wh, wt, x, hid, (u16*)wt, (u16*)wt);
        gru_fused_slow<<<1024, 256, 0, stream>>>(x, hid, wt, bx, bh, out);
    }
}

// Round 7
// 330.358 us; speedup vs baseline: 1.1702x; 1.1702x over previous
//
#include <hip/hip_runtime.h>
#include <hip/hip_bf16.h>

typedef __hip_bfloat16 bf16;
typedef unsigned short u16;
typedef __attribute__((ext_vector_type(8))) short bf16x8;     // MFMA A/B frag: 8 bf16 = 4 VGPRs
typedef __attribute__((ext_vector_type(4))) float f32x4;      // MFMA C/D frag
typedef __attribute__((ext_vector_type(8))) unsigned short u16x8;

#define KD 1024
#define HD 1024
#define BSZ 8192
#define BM 128
#define BN 64
#define BK 32
#define NT (KD / BK)

// ws layout (bytes): wt [0, 12582912) | xb [12582912, +16777216) | hb [29360128, +16777216)
#define WS_XB 12582912
#define WS_HB 29360128
#define WS_NEED 46137344ULL

#define NTRB 1536          // transpose job count (6 gates x 256 tiles)

__device__ __forceinline__ u16 f2b(float f) {
    return __builtin_bit_cast(u16, __float2bfloat16(f));
}

// ---- async global->LDS, 16B per lane, wave-uniform LDS base + lane*16 ----
__device__ __forceinline__ void gload16(const void* g, u16* smem, int lds_byte_off) {
    __builtin_amdgcn_global_load_lds(
        (const __attribute__((address_space(1))) void*)g,
        (__attribute__((address_space(3))) void*)((char*)smem + lds_byte_off),
        16, 0, 0);
}

// ---------------------------------------------------------------------------
// prep: ONE launch doing both aux jobs (R4 structure).
//   blocks [0,1536):    transpose+cast w [g][k][n] f32 -> wt[g][n][k] bf16.
//     f32 LDS tile [64][69]: both sides conflict-free (69 mod 32 = 5).
//   blocks [1536,5632): f32 -> bf16 streaming convert of x and hid.
// ---------------------------------------------------------------------------
__global__ __launch_bounds__(256) void prep(
    const float* __restrict__ wx, const float* __restrict__ wh, u16* __restrict__ wt,
    const float* __restrict__ x, const float* __restrict__ h,
    u16* __restrict__ xb, u16* __restrict__ hb)
{
    __shared__ float tile[64 * 69];
    const int b = blockIdx.x;
    const int t = threadIdx.x;

    if (b < NTRB) {
        const int g  = b >> 8;
        const int rm = b & 255;
        const int r0 = (rm >> 4) * 64;   // k origin in src
        const int c0 = (rm & 15) * 64;   // n origin in src
        const float* src = (g < 3) ? (wx + (size_t)g * KD * HD)
                                   : (wh + (size_t)(g - 3) * KD * HD);
        u16* dst = wt + (size_t)g * KD * HD;

        #pragma unroll
        for (int ps = 0; ps < 4; ps++) {
            int idx = ps * 256 + t;
            int row = idx >> 4;              // k row 0..63
            int c4  = (idx & 15) * 4;        // 4 n per thread
            float4 v = *(const float4*)(src + (size_t)(r0 + row) * HD + c0 + c4);
            *(float4*)&tile[row * 69 + c4] = v;
        }
        __syncthreads();
        const int n = t >> 2;                // output n-row 0..63
        #pragma unroll
        for (int p = 0; p < 2; p++) {
            int k0 = (t & 3) * 8 + p * 32;   // 8 k per store
            u16x8 v;
            #pragma unroll
            for (int e = 0; e < 8; e++)
                v[e] = f2b(tile[(k0 + e) * 69 + n]);
            *(u16x8*)(dst + (size_t)(c0 + n) * KD + r0 + k0) = v;
        }
    } else {
        size_t off = ((size_t)(b - NTRB) * 256 + t) * 8;
        float4 a0 = *(const float4*)(x + off);
        float4 a1 = *(const float4*)(x + off + 4);
        float4 b0 = *(const float4*)(h + off);
        float4 b1 = *(const float4*)(h + off + 4);
        u16x8 vx, vh;
        vx[0]=f2b(a0.x); vx[1]=f2b(a0.y); vx[2]=f2b(a0.z); vx[3]=f2b(a0.w);
        vx[4]=f2b(a1.x); vx[5]=f2b(a1.y); vx[6]=f2b(a1.z); vx[7]=f2b(a1.w);
        vh[0]=f2b(b0.x); vh[1]=f2b(b0.y); vh[2]=f2b(b0.z); vh[3]=f2b(b0.w);
        vh[4]=f2b(b1.x); vh[5]=f2b(b1.y); vh[6]=f2b(b1.z); vh[7]=f2b(b1.w);
        *(u16x8*)(xb + off) = vx;
        *(u16x8*)(hb + off) = vh;
    }
}

// ---------------------------------------------------------------------------
// Epilogue. C/D layout: col=lane&15, row=quad*4+r.
// ---------------------------------------------------------------------------
__device__ __forceinline__ void gru_epilogue(
    f32x4 (&acc)[4][4][2], const float* __restrict__ bxf, const float* __restrict__ bhf,
    const float* __restrict__ hidf, float* __restrict__ outf,
    int m0, int n0, int wm, int wn, int quad, int c16)
{
    float bR[2], bZ[2], bXN[2], bHN[2];
    #pragma unroll
    for (int j = 0; j < 2; j++) {
        int col = n0 + wn * 32 + j * 16 + c16;
        bR[j]  = bxf[col]          + bhf[col];
        bZ[j]  = bxf[HD + col]     + bhf[HD + col];
        bXN[j] = bxf[2 * HD + col];
        bHN[j] = bhf[2 * HD + col];
    }
    #pragma unroll
    for (int i = 0; i < 4; i++)
        #pragma unroll
        for (int j = 0; j < 2; j++) {
            int col = n0 + wn * 32 + j * 16 + c16;
            #pragma unroll
            for (int r = 0; r < 4; r++) {
                int row = m0 + wm * 64 + i * 16 + quad * 4 + r;
                size_t idx = (size_t)row * HD + col;
                float vr = acc[0][i][j][r] + bR[j];
                vr = 1.f / (1.f + __expf(-vr));
                float vz = acc[1][i][j][r] + bZ[j];
                vz = 1.f / (1.f + __expf(-vz));
                float vn = (acc[2][i][j][r] + bXN[j]) + vr * (acc[3][i][j][r] + bHN[j]);
                float e2 = __expf(2.f * vn);
                vn = 1.f - 2.f / (e2 + 1.f);
                float o = (1.f - vz) * vn + vz * hidf[idx];
                outf[idx] = o;
            }
        }
}

// ---------------------------------------------------------------------------
// MFMA block: A fragments from swizzled LDS, B fragments already in registers
// (loaded direct from L2-resident wt).
// ---------------------------------------------------------------------------
__device__ __forceinline__ void mfma_all(
    const bf16x8 (&ax)[4], const bf16x8 (&ah)[4], const bf16x8 (&bw)[6][2],
    f32x4 (&acc)[4][4][2])
{
    #pragma unroll
    for (int p = 0; p < 3; p++) {
        #pragma unroll
        for (int i = 0; i < 4; i++)
            #pragma unroll
            for (int j = 0; j < 2; j++) {
                if (p < 2) {
                    acc[p][i][j] = __builtin_amdgcn_mfma_f32_16x16x32_bf16(ax[i], bw[p][j],     acc[p][i][j], 0, 0, 0);
                    acc[p][i][j] = __builtin_amdgcn_mfma_f32_16x16x32_bf16(ah[i], bw[p + 3][j], acc[p][i][j], 0, 0, 0);
                } else {
                    acc[2][i][j] = __builtin_amdgcn_mfma_f32_16x16x32_bf16(ax[i], bw[2][j], acc[2][i][j], 0, 0, 0);
                    acc[3][i][j] = __builtin_amdgcn_mfma_f32_16x16x32_bf16(ah[i], bw[5][j], acc[3][i][j], 0, 0, 0);
                }
            }
    }
}

// ---------------------------------------------------------------------------
// Kernel C (fast), round-6 structure (resubmitted after infra failure):
//   - x/h staged via swizzled global_load_lds, double-buffered 16 KB
//     (conflict-free ds_reads, verified R3).
//   - WEIGHTS READ DIRECT FROM GLOBAL (L2-resident via XCD swizzle): per
//     K-step each wave issues 12 b128 loads; lanes {l,l+16,l+32,l+48} cover
//     contiguous 64 B of one n-row -> 16x64B sectors per load, same line
//     count as a coalesced load. Removes 72 KB/block-step of LDS traffic
//     (was at the measured ~106 B/cy LDS-BW roofline).
//   - One __syncthreads per K-step; its vmcnt(0) drain covers only the 4
//     x/h stage loads (issued ~2000 cy earlier).
// LDS: 2 x 16 KB = 32 KiB. Occupancy: 2 blocks/CU (VGPR-limited).
// ---------------------------------------------------------------------------
__global__ __launch_bounds__(256, 2) void gru_fused_fast(
    const u16* __restrict__ xb, const u16* __restrict__ hb,
    const u16* __restrict__ wt,
    const float* __restrict__ bxf, const float* __restrict__ bhf,
    const float* __restrict__ hidf, float* __restrict__ outf)
{
    __shared__ u16 smem[16384];   // 32 KiB: two 16 KiB x/h buffers
    const int t    = threadIdx.x;
    const int lane = t & 63;
    const int w    = t >> 6;
    const int wm   = w >> 1, wn = w & 1;
    const int quad = lane >> 4;
    const int c16  = lane & 15;
    // XCD swizzle: linear % 8 presumed XCD; each XCD owns 2 n-blocks so its
    // 1.57 MB weight slice stays L2-resident (critical for B-direct reads).
    const int lin  = blockIdx.x;
    const int nblk = (lin & 7) * 2 + ((lin >> 3) & 1);
    const int mblk = lin >> 4;
    const int m0   = mblk * BM;
    const int n0   = nblk * BN;

    // x/h staging: lane t writes LDS (row=t>>2, 16B-slot=t&3); source k-slot
    // XOR'd so physical slot p holds logical p ^ ((row>>1)&3) (involution).
    const int row4 = t >> 2;
    const int e8s  = ((t & 3) ^ ((t >> 3) & 3)) * 8;
    const u16* gx0 = xb + (size_t)(m0 + row4) * KD + e8s;
    const u16* gx1 = gx0 + (size_t)64 * KD;
    const u16* gh0 = hb + (size_t)(m0 + row4) * KD + e8s;
    const u16* gh1 = gh0 + (size_t)64 * KD;
    const int ldsl = w * 1024;   // wave-uniform LDS byte base (lane adds *16)

    // B-direct per-lane row bases (j=0 / j=1 half-fragments)
    const u16* pb0 = wt + (size_t)(n0 + wn * 32 + c16) * KD + quad * 8;
    const u16* pb1 = pb0 + (size_t)16 * KD;

    f32x4 acc[4][4][2];
    #pragma unroll
    for (int a = 0; a < 4; a++)
        #pragma unroll
        for (int i = 0; i < 4; i++)
            #pragma unroll
            for (int j = 0; j < 2; j++)
                acc[a][i][j] = (f32x4){0.f, 0.f, 0.f, 0.f};

    // prologue: stage x/h K-step 0 into buf 0, drain, barrier
    gload16(gx0, smem, 0     + ldsl);
    gload16(gx1, smem, 4096  + ldsl);
    gload16(gh0, smem, 8192  + ldsl);
    gload16(gh1, smem, 12288 + ldsl);
    gx0 += BK; gx1 += BK; gh0 += BK; gh1 += BK;
    __syncthreads();

    for (int tt = 0; tt < NT; ++tt) {
        // 1. issue B loads for THIS step (L2-resident, longest latency first)
        bf16x8 bw[6][2];
        #pragma unroll
        for (int g = 0; g < 6; g++) {
            bw[g][0] = *(const bf16x8*)(pb0 + (size_t)g * KD * HD);
            bw[g][1] = *(const bf16x8*)(pb1 + (size_t)g * KD * HD);
        }
        pb0 += BK; pb1 += BK;

        // 2. stage x/h for NEXT step into the other buffer
        if (tt < NT - 1) {
            int bufb = ((tt + 1) & 1) * 16384;
            gload16(gx0, smem, bufb + ldsl);
            gload16(gx1, smem, bufb + 4096 + ldsl);
            gload16(gh0, smem, bufb + 8192 + ldsl);
            gload16(gh1, smem, bufb + 12288 + ldsl);
            gx0 += BK; gx1 += BK; gh0 += BK; gh1 += BK;
        }

        // 3. A fragments from current buffer (swizzled, conflict-free)
        const u16* sm = smem + (tt & 1) * 8192;
        bf16x8 ax[4], ah[4];
        #pragma unroll
        for (int i = 0; i < 4; i++) {
            int ml = wm * 64 + i * 16 + c16;
            int sl = (quad ^ ((ml >> 1) & 3)) * 8;
            ax[i] = *(const bf16x8*)&sm[ml * BK + sl];
            ah[i] = *(const bf16x8*)&sm[4096 + ml * BK + sl];
        }

        // 4. MFMA (compiler inserts counted vmcnt for bw, lgkmcnt for ax/ah)
        mfma_all(ax, ah, bw, acc);

        if (tt < NT - 1) __syncthreads();
    }

    gru_epilogue(acc, bxf, bhf, hidf, outf, m0, n0, wm, wn, quad, c16);
}

// ---------------------------------------------------------------------------
// Fallback (ws too small for xb/hb): R3/R4 full-LDS path, unchanged.
// ---------------------------------------------------------------------------
__device__ __forceinline__ void kstep_compute_lds(
    const u16* sm, f32x4 (&acc)[4][4][2], int wm, int wn, int quad, int c16)
{
    bf16x8 ax[4], ah[4];
    #pragma unroll
    for (int i = 0; i < 4; i++) {
        int ml = wm * 64 + i * 16 + c16;
        int sl = (quad ^ ((ml >> 1) & 3)) * 8;
        ax[i] = *(const bf16x8*)&sm[ml * BK + sl];
        ah[i] = *(const bf16x8*)&sm[4096 + ml * BK + sl];
    }
    #pragma unroll
    for (int p = 0; p < 3; p++) {
        bf16x8 bwx[2], bwh[2];
        #pragma unroll
        for (int j = 0; j < 2; j++) {
            int nl = wn * 32 + j * 16 + c16;
            int sl = (quad ^ ((nl >> 1) & 3)) * 8;
            bwx[j] = *(const bf16x8*)&sm[8192 + p * 2048       + nl * BK + sl];
            bwh[j] = *(const bf16x8*)&sm[8192 + (p + 3) * 2048 + nl * BK + sl];
        }
        #pragma unroll
        for (int i = 0; i < 4; i++)
            #pragma unroll
            for (int j = 0; j < 2; j++) {
                if (p < 2) {
                    acc[p][i][j] = __builtin_amdgcn_mfma_f32_16x16x32_bf16(ax[i], bwx[j], acc[p][i][j], 0, 0, 0);
                    acc[p][i][j] = __builtin_amdgcn_mfma_f32_16x16x32_bf16(ah[i], bwh[j], acc[p][i][j], 0, 0, 0);
                } else {
                    acc[2][i][j] = __builtin_amdgcn_mfma_f32_16x16x32_bf16(ax[i], bwx[j], acc[2][i][j], 0, 0, 0);
                    acc[3][i][j] = __builtin_amdgcn_mfma_f32_16x16x32_bf16(ah[i], bwh[j], acc[3][i][j], 0, 0, 0);
                }
            }
    }
}

__global__ __launch_bounds__(256, 2) void gru_fused_slow(
    const float* __restrict__ xf, const float* __restrict__ hf,
    const u16* __restrict__ wt,
    const float* __restrict__ bxf, const float* __restrict__ bhf,
    float* __restrict__ outf)
{
    __shared__ u16 smem[20480];
    const int t    = threadIdx.x;
    const int lane = t & 63;
    const int w    = t >> 6;
    const int wm   = w >> 1, wn = w & 1;
    const int quad = lane >> 4;
    const int c16  = lane & 15;
    const int lin  = blockIdx.x;
    const int nblk = (lin & 7) * 2 + ((lin >> 3) & 1);
    const int mblk = lin >> 4;
    const int m0   = mblk * BM;
    const int n0   = nblk * BN;
    const int row4 = t >> 2;
    const int e8s  = ((t & 3) ^ ((t >> 3) & 3)) * 8;
    const u16* gw0 = wt + (size_t)(n0 + row4) * KD + e8s;
    const int ldsl = w * 1024;

    f32x4 acc[4][4][2];
    #pragma unroll
    for (int a = 0; a < 4; a++)
        #pragma unroll
        for (int i = 0; i < 4; i++)
            #pragma unroll
            for (int j = 0; j < 2; j++)
                acc[a][i][j] = (f32x4){0.f, 0.f, 0.f, 0.f};

    for (int k0 = 0; k0 < KD; k0 += BK) {
        #pragma unroll
        for (int g = 0; g < 6; g++)
            gload16(gw0 + (size_t)g * KD * HD, smem, 16384 + g * 4096 + ldsl);
        gw0 += BK;
        #pragma unroll
        for (int s = 0; s < 2; s++) {
            size_t gidx = (size_t)(m0 + s * 64 + row4) * KD + k0 + (t & 3) * 8;
            const float* px = xf + gidx;
            const float* ph = hf + gidx;
            u16x8 vx, vh;
            #pragma unroll
            for (int e = 0; e < 8; e++) { vx[e] = f2b(px[e]); vh[e] = f2b(ph[e]); }
            *(u16x8*)&smem[s * 2048 + row4 * 32 + e8s] = vx;
            *(u16x8*)&smem[4096 + s * 2048 + row4 * 32 + e8s] = vh;
        }
        __syncthreads();
        kstep_compute_lds(smem, acc, wm, wn, quad, c16);
        __syncthreads();
    }

    gru_epilogue(acc, bxf, bhf, hf, outf, m0, n0, wm, wn, quad, c16);
}

extern "C" void kernel_launch(void* const* d_in, const int* in_sizes, int n_in,
                              void* d_out, int out_size, void* d_ws, size_t ws_size,
                              hipStream_t stream) {
    const float* x   = (const float*)d_in[0];
    const float* hid = (const float*)d_in[1];
    const float* wx  = (const float*)d_in[2];
    const float* wh  = (const float*)d_in[3];
    const float* bx  = (const float*)d_in[4];
    const float* bh  = (const float*)d_in[5];
    float* out = (float*)d_out;

    char* ws = (char*)d_ws;
    u16* wt = (u16*)ws;
    u16* xb = (u16*)(ws + WS_XB);
    u16* hb = (u16*)(ws + WS_HB);

    if (ws_size >= WS_NEED) {
        prep<<<NTRB + 4096, 256, 0, stream>>>(wx, wh, wt, x, hid, xb, hb);
        gru_fused_fast<<<1024, 256, 0, stream>>>(xb, hb, wt, bx, bh, hid, out);
    } else {
        prep<<<NTRB, 256, 0, stream>>>(wx, wh, wt, x, hid, (u16*)wt, (u16*)wt);
        gru_fused_slow<<<1024, 256, 0, stream>>>(x, hid, wt, bx, bh, out);
    }
}

// Round 8
// 242.368 us; speedup vs baseline: 1.5950x; 1.3630x over previous
//
#include <hip/hip_runtime.h>
#include <hip/hip_bf16.h>

typedef __hip_bfloat16 bf16;
typedef unsigned short u16;
typedef __attribute__((ext_vector_type(8))) short bf16x8;     // MFMA A/B frag: 8 bf16 = 4 VGPRs
typedef __attribute__((ext_vector_type(4))) float f32x4;      // MFMA C/D frag
typedef __attribute__((ext_vector_type(8))) unsigned short u16x8;

#define KD 1024
#define HD 1024
#define BSZ 8192
#define BM 256
#define BN 64
#define BK 32
#define NT (KD / BK)

// ws layout (bytes): wt [0, 12582912) | xb [12582912, +16777216) | hb [29360128, +16777216)
#define WS_XB 12582912
#define WS_HB 29360128
#define WS_NEED 46137344ULL

__device__ __forceinline__ u16 f2b(float f) {
    return __builtin_bit_cast(u16, __float2bfloat16(f));
}

// ---- async global->LDS, 16B per lane, wave-uniform LDS base + lane*16 ----
__device__ __forceinline__ void gload16(const void* g, u16* smem, int lds_byte_off) {
    __builtin_amdgcn_global_load_lds(
        (const __attribute__((address_space(1))) void*)g,
        (__attribute__((address_space(3))) void*)((char*)smem + lds_byte_off),
        16, 0, 0);
}

// ---------------------------------------------------------------------------
// Kernel A: one-shot f32 -> bf16 conversion of x and hid (separate launch:
// R3's split-aux measured 35 us vs merged prep's 43).
// ---------------------------------------------------------------------------
__global__ __launch_bounds__(256) void convert_xh(
    const float* __restrict__ x, const float* __restrict__ h,
    u16* __restrict__ xb, u16* __restrict__ hb)
{
    size_t off = ((size_t)blockIdx.x * 256 + threadIdx.x) * 8;   // <<<4096,256>>>
    float4 a0 = *(const float4*)(x + off);
    float4 a1 = *(const float4*)(x + off + 4);
    float4 b0 = *(const float4*)(h + off);
    float4 b1 = *(const float4*)(h + off + 4);
    u16x8 vx, vh;
    vx[0]=f2b(a0.x); vx[1]=f2b(a0.y); vx[2]=f2b(a0.z); vx[3]=f2b(a0.w);
    vx[4]=f2b(a1.x); vx[5]=f2b(a1.y); vx[6]=f2b(a1.z); vx[7]=f2b(a1.w);
    vh[0]=f2b(b0.x); vh[1]=f2b(b0.y); vh[2]=f2b(b0.z); vh[3]=f2b(b0.w);
    vh[4]=f2b(b1.x); vh[5]=f2b(b1.y); vh[6]=f2b(b1.z); vh[7]=f2b(b1.w);
    *(u16x8*)(xb + off) = vx;
    *(u16x8*)(hb + off) = vh;
}

// ---------------------------------------------------------------------------
// Kernel B: transpose+cast w [g][k][n] f32 -> wt[g][n][k] bf16 (b128 both
// sides; f32 tile [64][69]: 69 mod 32 = 5 -> conflict-free write AND read).
// ---------------------------------------------------------------------------
__global__ __launch_bounds__(256) void transpose_w(
    const float* __restrict__ wx, const float* __restrict__ wh, u16* __restrict__ wt)
{
    __shared__ float tile[64 * 69];
    const int b = blockIdx.x;          // 1536 = 6 gates x 256 tiles
    const int t = threadIdx.x;
    const int g  = b >> 8;
    const int rm = b & 255;
    const int r0 = (rm >> 4) * 64;     // k origin in src
    const int c0 = (rm & 15) * 64;     // n origin in src
    const float* src = (g < 3) ? (wx + (size_t)g * KD * HD)
                               : (wh + (size_t)(g - 3) * KD * HD);
    u16* dst = wt + (size_t)g * KD * HD;

    #pragma unroll
    for (int ps = 0; ps < 4; ps++) {
        int idx = ps * 256 + t;
        int row = idx >> 4;            // k row 0..63
        int c4  = (idx & 15) * 4;      // 4 n per thread
        float4 v = *(const float4*)(src + (size_t)(r0 + row) * HD + c0 + c4);
        *(float4*)&tile[row * 69 + c4] = v;
    }
    __syncthreads();
    const int n = t >> 2;              // output n-row 0..63
    #pragma unroll
    for (int p = 0; p < 2; p++) {
        int k0 = (t & 3) * 8 + p * 32; // 8 k per store
        u16x8 v;
        #pragma unroll
        for (int e = 0; e < 8; e++)
            v[e] = f2b(tile[(k0 + e) * 69 + n]);
        *(u16x8*)(dst + (size_t)(c0 + n) * KD + r0 + k0) = v;
    }
}

// ---------------------------------------------------------------------------
// Epilogue. C/D layout: col=lane&15, row=quad*4+r.
// ---------------------------------------------------------------------------
__device__ __forceinline__ void gru_epilogue(
    f32x4 (&acc)[4][4][2], const float* __restrict__ bxf, const float* __restrict__ bhf,
    const float* __restrict__ hidf, float* __restrict__ outf,
    int m0, int n0, int wm, int wn, int quad, int c16)
{
    float bR[2], bZ[2], bXN[2], bHN[2];
    #pragma unroll
    for (int j = 0; j < 2; j++) {
        int col = n0 + wn * 32 + j * 16 + c16;
        bR[j]  = bxf[col]          + bhf[col];
        bZ[j]  = bxf[HD + col]     + bhf[HD + col];
        bXN[j] = bxf[2 * HD + col];
        bHN[j] = bhf[2 * HD + col];
    }
    #pragma unroll
    for (int i = 0; i < 4; i++)
        #pragma unroll
        for (int j = 0; j < 2; j++) {
            int col = n0 + wn * 32 + j * 16 + c16;
            #pragma unroll
            for (int r = 0; r < 4; r++) {
                int row = m0 + wm * 64 + i * 16 + quad * 4 + r;
                size_t idx = (size_t)row * HD + col;
                float vr = acc[0][i][j][r] + bR[j];
                vr = 1.f / (1.f + __expf(-vr));
                float vz = acc[1][i][j][r] + bZ[j];
                vz = 1.f / (1.f + __expf(-vz));
                float vn = (acc[2][i][j][r] + bXN[j]) + vr * (acc[3][i][j][r] + bHN[j]);
                float e2 = __expf(2.f * vn);
                vn = 1.f - 2.f / (e2 + 1.f);
                float o = (1.f - vz) * vn + vz * hidf[idx];
                outf[idx] = o;
            }
        }
}

// ---------------------------------------------------------------------------
// Kernel C (fast), BM=256 / 512-thread / 1-block-per-CU variant.
// Rationale: GEMM is LDS-BW-bound (measured 106 B/cy/CU vs ~112 ceiling).
// Reads/FLOP are pinned by the 128-VGPR acc budget, but WRITE traffic is
// halved by staging weights once per CU (one 256-row block) instead of
// twice (two 128-row blocks): 240 -> 216 KB/CU-step.
// LDS buffer (bytes): x [0,16K) h [16K,32K) w[g] [32K+g*4K) = 56 KB.
// Double-buffered = 112 KB. 8 waves = 4wm x 2wn, each 64x32 out (same
// per-wave shape, swizzle, and read pattern as the verified R3 kernel).
// 7 global_load_lds per step (512 thr x 16 B = 8 KB each).
// ---------------------------------------------------------------------------
__global__ __launch_bounds__(512, 2) void gru_fused_fast(
    const u16* __restrict__ xb, const u16* __restrict__ hb,
    const u16* __restrict__ wt,
    const float* __restrict__ bxf, const float* __restrict__ bhf,
    const float* __restrict__ hidf, float* __restrict__ outf)
{
    __shared__ u16 smem[57344];   // 112 KiB: two 57344-byte buffers
    const int t    = threadIdx.x;          // 0..511
    const int lane = t & 63;
    const int w    = t >> 6;               // 0..7
    const int wm   = w >> 1, wn = w & 1;   // wm 0..3, wn 0..1
    const int quad = lane >> 4;
    const int c16  = lane & 15;
    // XCD swizzle: linear % 8 presumed XCD; each XCD owns 2 n-blocks so its
    // 1.57 MB weight slice stays L2-resident. 512 blocks, 512%8==0 ✓.
    const int lin  = blockIdx.x;
    const int nblk = (lin & 7) * 2 + ((lin >> 3) & 1);
    const int mblk = lin >> 4;             // 0..31
    const int m0   = mblk * BM;
    const int n0   = nblk * BN;

    // Staging geometry (512 threads): row4 = t>>2 in 0..127, 16B-slot = t&3.
    // Source k-slot XOR'd so physical slot p holds logical p ^ ((row>>1)&3)
    // (involution; read side applies the same XOR). (t>>3)&3 == (row>>1)&3
    // for both the row4 and 128+row4 halves (128 ≡ 0 mod 4 after >>1).
    const int row4 = t >> 2;
    const int e8s  = ((t & 3) ^ ((t >> 3) & 3)) * 8;
    const u16* gxa = xb + (size_t)(m0 + row4) * KD + e8s;
    const u16* gxb = gxa + (size_t)128 * KD;
    const u16* gha = hb + (size_t)(m0 + row4) * KD + e8s;
    const u16* ghb = gha + (size_t)128 * KD;
    // weight calls c=0..2 cover slabs {2c, 2c+1}: threads <256 -> slab 2c,
    // threads >=256 -> slab 2c+1 (linear LDS byte t*16 lands there).
    const int wrow = (t >> 2) & 63;
    const int wsel = (t >> 8) & 1;
    const u16* gw0 = wt + (size_t)(0 + wsel) * KD * HD + (size_t)(n0 + wrow) * KD + e8s;
    const u16* gw1 = wt + (size_t)(2 + wsel) * KD * HD + (size_t)(n0 + wrow) * KD + e8s;
    const u16* gw2 = wt + (size_t)(4 + wsel) * KD * HD + (size_t)(n0 + wrow) * KD + e8s;
    const int ldsl = w * 1024;   // wave-uniform LDS byte base (lane adds *16)

    f32x4 acc[4][4][2];
    #pragma unroll
    for (int a = 0; a < 4; a++)
        #pragma unroll
        for (int i = 0; i < 4; i++)
            #pragma unroll
            for (int j = 0; j < 2; j++)
                acc[a][i][j] = (f32x4){0.f, 0.f, 0.f, 0.f};

    // ---- stage one K-step tile set into buffer at byte base bufb ----
    auto stage = [&](int bufb) {
        gload16(gxa, smem, bufb + 0     + ldsl);   // x rows   0..127
        gload16(gxb, smem, bufb + 8192  + ldsl);   // x rows 128..255
        gload16(gha, smem, bufb + 16384 + ldsl);   // h rows   0..127
        gload16(ghb, smem, bufb + 24576 + ldsl);   // h rows 128..255
        gload16(gw0, smem, bufb + 32768 + ldsl);   // w slabs 0,1
        gload16(gw1, smem, bufb + 40960 + ldsl);   // w slabs 2,3
        gload16(gw2, smem, bufb + 49152 + ldsl);   // w slabs 4,5
        gxa += BK; gxb += BK; gha += BK; ghb += BK;
        gw0 += BK; gw1 += BK; gw2 += BK;
    };

    // ---- compute one K-step from buffer at u16 pointer sm ----
    auto compute = [&](const u16* sm) {
        bf16x8 ax[4], ah[4];
        #pragma unroll
        for (int i = 0; i < 4; i++) {
            int ml = wm * 64 + i * 16 + c16;            // 0..255
            int sl = (quad ^ ((ml >> 1) & 3)) * 8;
            ax[i] = *(const bf16x8*)&sm[ml * 32 + sl];
            ah[i] = *(const bf16x8*)&sm[8192 + ml * 32 + sl];
        }
        #pragma unroll
        for (int p = 0; p < 3; p++) {
            bf16x8 bwx[2], bwh[2];
            #pragma unroll
            for (int j = 0; j < 2; j++) {
                int nl = wn * 32 + j * 16 + c16;        // 0..63
                int sl = (quad ^ ((nl >> 1) & 3)) * 8;
                bwx[j] = *(const bf16x8*)&sm[16384 + p * 2048       + nl * 32 + sl];
                bwh[j] = *(const bf16x8*)&sm[16384 + (p + 3) * 2048 + nl * 32 + sl];
            }
            #pragma unroll
            for (int i = 0; i < 4; i++)
                #pragma unroll
                for (int j = 0; j < 2; j++) {
                    if (p < 2) {
                        acc[p][i][j] = __builtin_amdgcn_mfma_f32_16x16x32_bf16(ax[i], bwx[j], acc[p][i][j], 0, 0, 0);
                        acc[p][i][j] = __builtin_amdgcn_mfma_f32_16x16x32_bf16(ah[i], bwh[j], acc[p][i][j], 0, 0, 0);
                    } else {
                        acc[2][i][j] = __builtin_amdgcn_mfma_f32_16x16x32_bf16(ax[i], bwx[j], acc[2][i][j], 0, 0, 0);
                        acc[3][i][j] = __builtin_amdgcn_mfma_f32_16x16x32_bf16(ah[i], bwh[j], acc[3][i][j], 0, 0, 0);
                    }
                }
        }
    };

    // prologue: stage k-step 0 into buffer 0, drain, barrier
    stage(0);
    __syncthreads();

    // steady state: stage t+1 into buf[(t+1)&1] while computing t from buf[t&1]
    for (int tt = 0; tt < NT - 1; ++tt) {
        stage(((tt + 1) & 1) * 57344);
        compute(smem + (tt & 1) * 28672);
        __syncthreads();
    }
    compute(smem + 28672);   // (NT-1)&1 == 1

    gru_epilogue(acc, bxf, bhf, hidf, outf, m0, n0, wm, wn, quad, c16);
}

// ---------------------------------------------------------------------------
// Fallback (ws too small for xb/hb): R3 full-LDS 128-tile path, unchanged.
// ---------------------------------------------------------------------------
__device__ __forceinline__ void kstep_compute_lds(
    const u16* sm, f32x4 (&acc)[4][4][2], int wm, int wn, int quad, int c16)
{
    bf16x8 ax[4], ah[4];
    #pragma unroll
    for (int i = 0; i < 4; i++) {
        int ml = wm * 64 + i * 16 + c16;
        int sl = (quad ^ ((ml >> 1) & 3)) * 8;
        ax[i] = *(const bf16x8*)&sm[ml * BK + sl];
        ah[i] = *(const bf16x8*)&sm[4096 + ml * BK + sl];
    }
    #pragma unroll
    for (int p = 0; p < 3; p++) {
        bf16x8 bwx[2], bwh[2];
        #pragma unroll
        for (int j = 0; j < 2; j++) {
            int nl = wn * 32 + j * 16 + c16;
            int sl = (quad ^ ((nl >> 1) & 3)) * 8;
            bwx[j] = *(const bf16x8*)&sm[8192 + p * 2048       + nl * BK + sl];
            bwh[j] = *(const bf16x8*)&sm[8192 + (p + 3) * 2048 + nl * BK + sl];
        }
        #pragma unroll
        for (int i = 0; i < 4; i++)
            #pragma unroll
            for (int j = 0; j < 2; j++) {
                if (p < 2) {
                    acc[p][i][j] = __builtin_amdgcn_mfma_f32_16x16x32_bf16(ax[i], bwx[j], acc[p][i][j], 0, 0, 0);
                    acc[p][i][j] = __builtin_amdgcn_mfma_f32_16x16x32_bf16(ah[i], bwh[j], acc[p][i][j], 0, 0, 0);
                } else {
                    acc[2][i][j] = __builtin_amdgcn_mfma_f32_16x16x32_bf16(ax[i], bwx[j], acc[2][i][j], 0, 0, 0);
                    acc[3][i][j] = __builtin_amdgcn_mfma_f32_16x16x32_bf16(ah[i], bwh[j], acc[3][i][j], 0, 0, 0);
                }
            }
    }
}

__global__ __launch_bounds__(256, 2) void gru_fused_slow(
    const float* __restrict__ xf, const float* __restrict__ hf,
    const u16* __restrict__ wt,
    const float* __restrict__ bxf, const float* __restrict__ bhf,
    float* __restrict__ outf)
{
    __shared__ u16 smem[20480];
    const int t    = threadIdx.x;
    const int lane = t & 63;
    const int w    = t >> 6;
    const int wm   = w >> 1, wn = w & 1;
    const int quad = lane >> 4;
    const int c16  = lane & 15;
    const int lin  = blockIdx.x;
    const int nblk = (lin & 7) * 2 + ((lin >> 3) & 1);
    const int mblk = lin >> 4;
    const int m0   = mblk * 128;
    const int n0   = nblk * BN;
    const int row4 = t >> 2;
    const int e8s  = ((t & 3) ^ ((t >> 3) & 3)) * 8;
    const u16* gw0 = wt + (size_t)(n0 + row4) * KD + e8s;
    const int ldsl = w * 1024;

    f32x4 acc[4][4][2];
    #pragma unroll
    for (int a = 0; a < 4; a++)
        #pragma unroll
        for (int i = 0; i < 4; i++)
            #pragma unroll
            for (int j = 0; j < 2; j++)
                acc[a][i][j] = (f32x4){0.f, 0.f, 0.f, 0.f};

    for (int k0 = 0; k0 < KD; k0 += BK) {
        #pragma unroll
        for (int g = 0; g < 6; g++)
            gload16(gw0 + (size_t)g * KD * HD, smem, 16384 + g * 4096 + ldsl);
        gw0 += BK;
        #pragma unroll
        for (int s = 0; s < 2; s++) {
            size_t gidx = (size_t)(m0 + s * 64 + row4) * KD + k0 + (t & 3) * 8;
            const float* px = xf + gidx;
            const float* ph = hf + gidx;
            u16x8 vx, vh;
            #pragma unroll
            for (int e = 0; e < 8; e++) { vx[e] = f2b(px[e]); vh[e] = f2b(ph[e]); }
            *(u16x8*)&smem[s * 2048 + row4 * 32 + e8s] = vx;
            *(u16x8*)&smem[4096 + s * 2048 + row4 * 32 + e8s] = vh;
        }
        __syncthreads();
        kstep_compute_lds(smem, acc, wm, wn, quad, c16);
        __syncthreads();
    }

    gru_epilogue(acc, bxf, bhf, hf, outf, m0, n0, wm, wn, quad, c16);
}

extern "C" void kernel_launch(void* const* d_in, const int* in_sizes, int n_in,
                              void* d_out, int out_size, void* d_ws, size_t ws_size,
                              hipStream_t stream) {
    const float* x   = (const float*)d_in[0];
    const float* hid = (const float*)d_in[1];
    const float* wx  = (const float*)d_in[2];
    const float* wh  = (const float*)d_in[3];
    const float* bx  = (const float*)d_in[4];
    const float* bh  = (const float*)d_in[5];
    float* out = (float*)d_out;

    char* ws = (char*)d_ws;
    u16* wt = (u16*)ws;
    u16* xb = (u16*)(ws + WS_XB);
    u16* hb = (u16*)(ws + WS_HB);

    transpose_w<<<1536, 256, 0, stream>>>(wx, wh, wt);

    if (ws_size >= WS_NEED) {
        convert_xh<<<4096, 256, 0, stream>>>(x, hid, xb, hb);
        gru_fused_fast<<<512, 512, 0, stream>>>(xb, hb, wt, bx, bh, hid, out);
    } else {
        gru_fused_slow<<<1024, 256, 0, stream>>>(x, hid, wt, bx, bh, out);
    }
}

// Round 9
// 241.638 us; speedup vs baseline: 1.5999x; 1.0030x over previous
//
#include <hip/hip_runtime.h>
#include <hip/hip_bf16.h>

typedef __hip_bfloat16 bf16;
typedef unsigned short u16;
typedef __attribute__((ext_vector_type(8))) short bf16x8;     // MFMA A/B frag: 8 bf16 = 4 VGPRs
typedef __attribute__((ext_vector_type(4))) float f32x4;      // MFMA C/D frag
typedef __attribute__((ext_vector_type(8))) unsigned short u16x8;

#define KD 1024
#define HD 1024
#define BSZ 8192
#define BM 256
#define BN 64
#define BK 32
#define NT (KD / BK)

// ws layout (bytes): wt [0, 12582912) | xb [12582912, +16777216) | hb [29360128, +16777216)
#define WS_XB 12582912
#define WS_HB 29360128
#define WS_NEED 46137344ULL

__device__ __forceinline__ u16 f2b(float f) {
    return __builtin_bit_cast(u16, __float2bfloat16(f));
}

// ---- async global->LDS, 16B per lane, wave-uniform LDS base + lane*16 ----
__device__ __forceinline__ void gload16(const void* g, u16* smem, int lds_byte_off) {
    __builtin_amdgcn_global_load_lds(
        (const __attribute__((address_space(1))) void*)g,
        (__attribute__((address_space(3))) void*)((char*)smem + lds_byte_off),
        16, 0, 0);
}

// ---------------------------------------------------------------------------
// Kernel A: one-shot f32 -> bf16 conversion of x and hid.
// ---------------------------------------------------------------------------
__global__ __launch_bounds__(256) void convert_xh(
    const float* __restrict__ x, const float* __restrict__ h,
    u16* __restrict__ xb, u16* __restrict__ hb)
{
    size_t off = ((size_t)blockIdx.x * 256 + threadIdx.x) * 8;   // <<<4096,256>>>
    float4 a0 = *(const float4*)(x + off);
    float4 a1 = *(const float4*)(x + off + 4);
    float4 b0 = *(const float4*)(h + off);
    float4 b1 = *(const float4*)(h + off + 4);
    u16x8 vx, vh;
    vx[0]=f2b(a0.x); vx[1]=f2b(a0.y); vx[2]=f2b(a0.z); vx[3]=f2b(a0.w);
    vx[4]=f2b(a1.x); vx[5]=f2b(a1.y); vx[6]=f2b(a1.z); vx[7]=f2b(a1.w);
    vh[0]=f2b(b0.x); vh[1]=f2b(b0.y); vh[2]=f2b(b0.z); vh[3]=f2b(b0.w);
    vh[4]=f2b(b1.x); vh[5]=f2b(b1.y); vh[6]=f2b(b1.z); vh[7]=f2b(b1.w);
    *(u16x8*)(xb + off) = vx;
    *(u16x8*)(hb + off) = vh;
}

// ---------------------------------------------------------------------------
// Kernel B: transpose+cast w [g][k][n] f32 -> wt[g][n][k] bf16 (b128 both
// sides; f32 tile [64][69]: 69 mod 32 = 5 -> conflict-free write AND read).
// ---------------------------------------------------------------------------
__global__ __launch_bounds__(256) void transpose_w(
    const float* __restrict__ wx, const float* __restrict__ wh, u16* __restrict__ wt)
{
    __shared__ float tile[64 * 69];
    const int b = blockIdx.x;          // 1536 = 6 gates x 256 tiles
    const int t = threadIdx.x;
    const int g  = b >> 8;
    const int rm = b & 255;
    const int r0 = (rm >> 4) * 64;     // k origin in src
    const int c0 = (rm & 15) * 64;     // n origin in src
    const float* src = (g < 3) ? (wx + (size_t)g * KD * HD)
                               : (wh + (size_t)(g - 3) * KD * HD);
    u16* dst = wt + (size_t)g * KD * HD;

    #pragma unroll
    for (int ps = 0; ps < 4; ps++) {
        int idx = ps * 256 + t;
        int row = idx >> 4;            // k row 0..63
        int c4  = (idx & 15) * 4;      // 4 n per thread
        float4 v = *(const float4*)(src + (size_t)(r0 + row) * HD + c0 + c4);
        *(float4*)&tile[row * 69 + c4] = v;
    }
    __syncthreads();
    const int n = t >> 2;              // output n-row 0..63
    #pragma unroll
    for (int p = 0; p < 2; p++) {
        int k0 = (t & 3) * 8 + p * 32; // 8 k per store
        u16x8 v;
        #pragma unroll
        for (int e = 0; e < 8; e++)
            v[e] = f2b(tile[(k0 + e) * 69 + n]);
        *(u16x8*)(dst + (size_t)(c0 + n) * KD + r0 + k0) = v;
    }
}

// ---------------------------------------------------------------------------
// Epilogue. C/D layout: col=lane&15, row=quad*4+r.
// ---------------------------------------------------------------------------
__device__ __forceinline__ void gru_epilogue(
    f32x4 (&acc)[4][4][2], const float* __restrict__ bxf, const float* __restrict__ bhf,
    const float* __restrict__ hidf, float* __restrict__ outf,
    int m0, int n0, int wm, int wn, int quad, int c16)
{
    float bR[2], bZ[2], bXN[2], bHN[2];
    #pragma unroll
    for (int j = 0; j < 2; j++) {
        int col = n0 + wn * 32 + j * 16 + c16;
        bR[j]  = bxf[col]          + bhf[col];
        bZ[j]  = bxf[HD + col]     + bhf[HD + col];
        bXN[j] = bxf[2 * HD + col];
        bHN[j] = bhf[2 * HD + col];
    }
    #pragma unroll
    for (int i = 0; i < 4; i++)
        #pragma unroll
        for (int j = 0; j < 2; j++) {
            int col = n0 + wn * 32 + j * 16 + c16;
            #pragma unroll
            for (int r = 0; r < 4; r++) {
                int row = m0 + wm * 64 + i * 16 + quad * 4 + r;
                size_t idx = (size_t)row * HD + col;
                float vr = acc[0][i][j][r] + bR[j];
                vr = 1.f / (1.f + __expf(-vr));
                float vz = acc[1][i][j][r] + bZ[j];
                vz = 1.f / (1.f + __expf(-vz));
                float vn = (acc[2][i][j][r] + bXN[j]) + vr * (acc[3][i][j][r] + bHN[j]);
                float e2 = __expf(2.f * vn);
                vn = 1.f - 2.f / (e2 + 1.f);
                float o = (1.f - vz) * vn + vz * hidf[idx];
                outf[idx] = o;
            }
        }
}

// ---------------------------------------------------------------------------
// Kernel C (fast): BM=256 / 512-thr / 8-wave, 3-PHASE SCHEDULE with COUNTED
// vmcnt (T3+T4) + setprio (T5). Evidence: three 2-phase configs all pin at
// 120.5-123 us / MfmaUtil 37% (the documented 2-phase lockstep plateau);
// LDS at 53 B/cy (half ceiling), HBM 20% -> the ~36% no-issue bubble is the
// serial chain, and counted-vmcnt phase-split is the catalog lever for it.
//
// Buffers (bytes): xh 3-deep: buf q at q*32768, x [0,16K) h [16K,32K).
//                  w  2-deep: buf q at 98304 + q*24576, slab g at g*4096.
// Total 144 KiB -> 1 block/CU (same occupancy as R8's 112 KiB).
//
// Per iter tt: phase p in {0,1,2}: {ds_read (A-frags in p0 + slab pair p),
//   stage issue (p0: w(t+1); p1: xh(t+2)) -> s_barrier -> setprio(1) ->
//   16 MFMA -> setprio(0) -> [p2 only: s_waitcnt vmcnt(4)] -> s_barrier}.
// vmcnt(4): FIFO = [... w(t+1)x3, xh(t+2)x4] -> leaves xh(t+2) in flight,
// guarantees xh(t+1) (issued last iter) and w(t+1) landed. Loads stay in
// flight across EVERY barrier (never drain to 0 until the tail).
// ---------------------------------------------------------------------------
__global__ __launch_bounds__(512, 2) void gru_fused_fast(
    const u16* __restrict__ xb, const u16* __restrict__ hb,
    const u16* __restrict__ wt,
    const float* __restrict__ bxf, const float* __restrict__ bhf,
    const float* __restrict__ hidf, float* __restrict__ outf)
{
    __shared__ u16 smem[73728];   // 144 KiB
    const int t    = threadIdx.x;          // 0..511
    const int lane = t & 63;
    const int w    = t >> 6;               // 0..7
    const int wm   = w >> 1, wn = w & 1;
    const int quad = lane >> 4;
    const int c16  = lane & 15;
    const int lin  = blockIdx.x;
    const int nblk = (lin & 7) * 2 + ((lin >> 3) & 1);   // XCD swizzle
    const int mblk = lin >> 4;
    const int m0   = mblk * BM;
    const int n0   = nblk * BN;

    // staging geometry (verified R8): source k-slot pre-XOR'd so linear
    // gload_lds write yields phys slot p = logical p ^ ((row>>1)&3).
    const int row4 = t >> 2;               // 0..127
    const int e8s  = ((t & 3) ^ ((t >> 3) & 3)) * 8;
    const u16* gxa = xb + (size_t)(m0 + row4) * KD + e8s;
    const u16* gxb = gxa + (size_t)128 * KD;
    const u16* gha = hb + (size_t)(m0 + row4) * KD + e8s;
    const u16* ghb = gha + (size_t)128 * KD;
    const int wrow = row4 & 63;
    const int wsel = (t >> 8) & 1;         // thread<256 -> slabs 0,2,4; else 1,3,5
    const u16* gw0 = wt + (size_t)(0 + wsel) * KD * HD + (size_t)(n0 + wrow) * KD + e8s;
    const u16* gw1 = wt + (size_t)(2 + wsel) * KD * HD + (size_t)(n0 + wrow) * KD + e8s;
    const u16* gw2 = wt + (size_t)(4 + wsel) * KD * HD + (size_t)(n0 + wrow) * KD + e8s;
    const int ldsl = w * 1024;             // wave-uniform byte base (+lane*16)

    f32x4 acc[4][4][2];
    #pragma unroll
    for (int a = 0; a < 4; a++)
        #pragma unroll
        for (int i = 0; i < 4; i++)
            #pragma unroll
            for (int j = 0; j < 2; j++)
                acc[a][i][j] = (f32x4){0.f, 0.f, 0.f, 0.f};

    // ---- stage one xh K-tile (32 KB) into xh buffer q (byte base q*32768)
    auto stage_xh = [&](int bufb) {
        gload16(gxa, smem, bufb + 0     + ldsl);   // x rows   0..127
        gload16(gxb, smem, bufb + 8192  + ldsl);   // x rows 128..255
        gload16(gha, smem, bufb + 16384 + ldsl);   // h rows   0..127
        gload16(ghb, smem, bufb + 24576 + ldsl);   // h rows 128..255
        gxa += BK; gxb += BK; gha += BK; ghb += BK;
    };
    // ---- stage one w K-tile (24 KB) into w buffer (byte base 98304+q*24576)
    auto stage_w = [&](int bufb) {
        gload16(gw0, smem, bufb + 0     + ldsl);   // slabs 0,1
        gload16(gw1, smem, bufb + 8192  + ldsl);   // slabs 2,3
        gload16(gw2, smem, bufb + 16384 + ldsl);   // slabs 4,5
        gw0 += BK; gw1 += BK; gw2 += BK;
    };

    // prologue: FIFO = xh(0) x4, w(0) x3, xh(1) x4; wait leaves xh(1) in flight
    stage_xh(0);
    stage_w(98304);
    stage_xh(32768);
    asm volatile("s_waitcnt vmcnt(4)" ::: "memory");
    __builtin_amdgcn_s_barrier();

    for (int tt = 0; tt < NT; ++tt) {
        const u16* smx = smem + (tt % 3) * 16384;            // u16 units
        const u16* smw = smem + 49152 + (tt & 1) * 12288;    // u16 units

        // ---------------- phase 0: A-frags + gate-pair 0 (slabs 0,3) -------
        bf16x8 ax[4], ah[4];
        #pragma unroll
        for (int i = 0; i < 4; i++) {
            int ml = wm * 64 + i * 16 + c16;
            int sl = (quad ^ ((ml >> 1) & 3)) * 8;
            ax[i] = *(const bf16x8*)&smx[ml * 32 + sl];
            ah[i] = *(const bf16x8*)&smx[8192 + ml * 32 + sl];
        }
        bf16x8 b0x[2], b0h[2];
        #pragma unroll
        for (int j = 0; j < 2; j++) {
            int nl = wn * 32 + j * 16 + c16;
            int sl = (quad ^ ((nl >> 1) & 3)) * 8;
            b0x[j] = *(const bf16x8*)&smw[0 * 2048 + nl * 32 + sl];
            b0h[j] = *(const bf16x8*)&smw[3 * 2048 + nl * 32 + sl];
        }
        if (tt + 1 < NT) stage_w(98304 + ((tt + 1) & 1) * 24576);
        __builtin_amdgcn_s_barrier();
        __builtin_amdgcn_s_setprio(1);
        #pragma unroll
        for (int i = 0; i < 4; i++)
            #pragma unroll
            for (int j = 0; j < 2; j++) {
                acc[0][i][j] = __builtin_amdgcn_mfma_f32_16x16x32_bf16(ax[i], b0x[j], acc[0][i][j], 0, 0, 0);
                acc[0][i][j] = __builtin_amdgcn_mfma_f32_16x16x32_bf16(ah[i], b0h[j], acc[0][i][j], 0, 0, 0);
            }
        __builtin_amdgcn_s_setprio(0);
        __builtin_amdgcn_s_barrier();

        // ---------------- phase 1: gate-pair 1 (slabs 1,4) -----------------
        bf16x8 b1x[2], b1h[2];
        #pragma unroll
        for (int j = 0; j < 2; j++) {
            int nl = wn * 32 + j * 16 + c16;
            int sl = (quad ^ ((nl >> 1) & 3)) * 8;
            b1x[j] = *(const bf16x8*)&smw[1 * 2048 + nl * 32 + sl];
            b1h[j] = *(const bf16x8*)&smw[4 * 2048 + nl * 32 + sl];
        }
        if (tt + 2 < NT) stage_xh(((tt + 2) % 3) * 32768);
        __builtin_amdgcn_s_barrier();
        __builtin_amdgcn_s_setprio(1);
        #pragma unroll
        for (int i = 0; i < 4; i++)
            #pragma unroll
            for (int j = 0; j < 2; j++) {
                acc[1][i][j] = __builtin_amdgcn_mfma_f32_16x16x32_bf16(ax[i], b1x[j], acc[1][i][j], 0, 0, 0);
                acc[1][i][j] = __builtin_amdgcn_mfma_f32_16x16x32_bf16(ah[i], b1h[j], acc[1][i][j], 0, 0, 0);
            }
        __builtin_amdgcn_s_setprio(0);
        __builtin_amdgcn_s_barrier();

        // ---------------- phase 2: gate-pair 2 (slabs 2,5) -----------------
        bf16x8 b2x[2], b2h[2];
        #pragma unroll
        for (int j = 0; j < 2; j++) {
            int nl = wn * 32 + j * 16 + c16;
            int sl = (quad ^ ((nl >> 1) & 3)) * 8;
            b2x[j] = *(const bf16x8*)&smw[2 * 2048 + nl * 32 + sl];
            b2h[j] = *(const bf16x8*)&smw[5 * 2048 + nl * 32 + sl];
        }
        __builtin_amdgcn_s_barrier();
        __builtin_amdgcn_s_setprio(1);
        #pragma unroll
        for (int i = 0; i < 4; i++)
            #pragma unroll
            for (int j = 0; j < 2; j++) {
                acc[2][i][j] = __builtin_amdgcn_mfma_f32_16x16x32_bf16(ax[i], b2x[j], acc[2][i][j], 0, 0, 0);
                acc[3][i][j] = __builtin_amdgcn_mfma_f32_16x16x32_bf16(ah[i], b2h[j], acc[3][i][j], 0, 0, 0);
            }
        __builtin_amdgcn_s_setprio(0);
        // counted wait: leave xh(tt+2)'s 4 loads in flight; tail drains to 0.
        if (tt + 2 < NT) { asm volatile("s_waitcnt vmcnt(4)" ::: "memory"); }
        else             { asm volatile("s_waitcnt vmcnt(0)" ::: "memory"); }
        __builtin_amdgcn_s_barrier();
    }

    gru_epilogue(acc, bxf, bhf, hidf, outf, m0, n0, wm, wn, quad, c16);
}

// ---------------------------------------------------------------------------
// Fallback (ws too small for xb/hb): R3 full-LDS 128-tile path, unchanged.
// ---------------------------------------------------------------------------
__device__ __forceinline__ void kstep_compute_lds(
    const u16* sm, f32x4 (&acc)[4][4][2], int wm, int wn, int quad, int c16)
{
    bf16x8 ax[4], ah[4];
    #pragma unroll
    for (int i = 0; i < 4; i++) {
        int ml = wm * 64 + i * 16 + c16;
        int sl = (quad ^ ((ml >> 1) & 3)) * 8;
        ax[i] = *(const bf16x8*)&sm[ml * BK + sl];
        ah[i] = *(const bf16x8*)&sm[4096 + ml * BK + sl];
    }
    #pragma unroll
    for (int p = 0; p < 3; p++) {
        bf16x8 bwx[2], bwh[2];
        #pragma unroll
        for (int j = 0; j < 2; j++) {
            int nl = wn * 32 + j * 16 + c16;
            int sl = (quad ^ ((nl >> 1) & 3)) * 8;
            bwx[j] = *(const bf16x8*)&sm[8192 + p * 2048       + nl * BK + sl];
            bwh[j] = *(const bf16x8*)&sm[8192 + (p + 3) * 2048 + nl * BK + sl];
        }
        #pragma unroll
        for (int i = 0; i < 4; i++)
            #pragma unroll
            for (int j = 0; j < 2; j++) {
                if (p < 2) {
                    acc[p][i][j] = __builtin_amdgcn_mfma_f32_16x16x32_bf16(ax[i], bwx[j], acc[p][i][j], 0, 0, 0);
                    acc[p][i][j] = __builtin_amdgcn_mfma_f32_16x16x32_bf16(ah[i], bwh[j], acc[p][i][j], 0, 0, 0);
                } else {
                    acc[2][i][j] = __builtin_amdgcn_mfma_f32_16x16x32_bf16(ax[i], bwx[j], acc[2][i][j], 0, 0, 0);
                    acc[3][i][j] = __builtin_amdgcn_mfma_f32_16x16x32_bf16(ah[i], bwh[j], acc[3][i][j], 0, 0, 0);
                }
            }
    }
}

__global__ __launch_bounds__(256, 2) void gru_fused_slow(
    const float* __restrict__ xf, const float* __restrict__ hf,
    const u16* __restrict__ wt,
    const float* __restrict__ bxf, const float* __restrict__ bhf,
    float* __restrict__ outf)
{
    __shared__ u16 smem[20480];
    const int t    = threadIdx.x;
    const int lane = t & 63;
    const int w    = t >> 6;
    const int wm   = w >> 1, wn = w & 1;
    const int quad = lane >> 4;
    const int c16  = lane & 15;
    const int lin  = blockIdx.x;
    const int nblk = (lin & 7) * 2 + ((lin >> 3) & 1);
    const int mblk = lin >> 4;
    const int m0   = mblk * 128;
    const int n0   = nblk * BN;
    const int row4 = t >> 2;
    const int e8s  = ((t & 3) ^ ((t >> 3) & 3)) * 8;
    const u16* gw0 = wt + (size_t)(n0 + row4) * KD + e8s;
    const int ldsl = w * 1024;

    f32x4 acc[4][4][2];
    #pragma unroll
    for (int a = 0; a < 4; a++)
        #pragma unroll
        for (int i = 0; i < 4; i++)
            #pragma unroll
            for (int j = 0; j < 2; j++)
                acc[a][i][j] = (f32x4){0.f, 0.f, 0.f, 0.f};

    for (int k0 = 0; k0 < KD; k0 += BK) {
        #pragma unroll
        for (int g = 0; g < 6; g++)
            gload16(gw0 + (size_t)g * KD * HD, smem, 16384 + g * 4096 + ldsl);
        gw0 += BK;
        #pragma unroll
        for (int s = 0; s < 2; s++) {
            size_t gidx = (size_t)(m0 + s * 64 + row4) * KD + k0 + (t & 3) * 8;
            const float* px = xf + gidx;
            const float* ph = hf + gidx;
            u16x8 vx, vh;
            #pragma unroll
            for (int e = 0; e < 8; e++) { vx[e] = f2b(px[e]); vh[e] = f2b(ph[e]); }
            *(u16x8*)&smem[s * 2048 + row4 * 32 + e8s] = vx;
            *(u16x8*)&smem[4096 + s * 2048 + row4 * 32 + e8s] = vh;
        }
        __syncthreads();
        kstep_compute_lds(smem, acc, wm, wn, quad, c16);
        __syncthreads();
    }

    gru_epilogue(acc, bxf, bhf, hf, outf, m0, n0, wm, wn, quad, c16);
}

extern "C" void kernel_launch(void* const* d_in, const int* in_sizes, int n_in,
                              void* d_out, int out_size, void* d_ws, size_t ws_size,
                              hipStream_t stream) {
    const float* x   = (const float*)d_in[0];
    const float* hid = (const float*)d_in[1];
    const float* wx  = (const float*)d_in[2];
    const float* wh  = (const float*)d_in[3];
    const float* bx  = (const float*)d_in[4];
    const float* bh  = (const float*)d_in[5];
    float* out = (float*)d_out;

    char* ws = (char*)d_ws;
    u16* wt = (u16*)ws;
    u16* xb = (u16*)(ws + WS_XB);
    u16* hb = (u16*)(ws + WS_HB);

    transpose_w<<<1536, 256, 0, stream>>>(wx, wh, wt);

    if (ws_size >= WS_NEED) {
        convert_xh<<<4096, 256, 0, stream>>>(x, hid, xb, hb);
        gru_fused_fast<<<512, 512, 0, stream>>>(xb, hb, wt, bx, bh, hid, out);
    } else {
        gru_fused_slow<<<1024, 256, 0, stream>>>(x, hid, wt, bx, bh, out);
    }
}